// Round 9
// baseline (163.587 us; speedup 1.0000x reference)
//
#include <hip/hip_runtime.h>

#define BIG 1e8f
#define LN2 0.69314718f
#define LOG2E 1.44269504f
#define M2L -2.8853900818f  /* -2*log2(e) */

#define RSLOT 76            /* band ring slots per batch */
#define DRB 1040            /* drow stride bytes: 256 cols * 4B(half2) + 16 pad */

/* per-batch LDS layout (PB bytes, 16-aligned) */
#define OFF_X2S 79040       /* band: [0, 79040) = 76*1040 */
#define OFF_Y2S 80064
#define OFF_RDY 81088       /* 16 ready flags */
#define OFF_PRG 81152       /* consumer progress */
#define PB      81168
#define LDS_BYTES (2 * PB)  /* 162336 <= 160 KiB */

typedef _Float16 half8 __attribute__((ext_vector_type(8)));
typedef _Float16 half2_t __attribute__((ext_vector_type(2)));
typedef float f32x4 __attribute__((ext_vector_type(4)));

__device__ __forceinline__ float exp2g(float x) {
#if __has_builtin(__builtin_amdgcn_exp2f)
    return __builtin_amdgcn_exp2f(x);
#else
    return exp2f(x);
#endif
}
__device__ __forceinline__ float log2g(float x) {
#if __has_builtin(__builtin_amdgcn_logf)
    return __builtin_amdgcn_logf(x);
#else
    return log2f(x);
#endif
}

__device__ __forceinline__ half2_t pkrtz(float a, float b) {
    return __builtin_bit_cast(half2_t, __builtin_amdgcn_cvt_pkrtz(a, b));
}

// whole-wave shift-up-by-1 via DPP wave_shr:1; lane 0 receives oldv.
__device__ __forceinline__ float shfl_up1(float v, float oldv) {
    int r = __builtin_amdgcn_update_dpp(
        __builtin_bit_cast(int, oldv), __builtin_bit_cast(int, v),
        0x138 /*wave_shr:1*/, 0xf, 0xf, false);
    return __builtin_bit_cast(float, r);
}

__device__ __forceinline__ void dec2(unsigned int w, float& a, float& b) {
    half2_t h = __builtin_bit_cast(half2_t, w);
    a = (float)h[0];
    b = (float)h[1];
}

// SELECTLESS 3-way softmin cell in exponential-pair form (v = M - log2(S)).
__device__ __forceinline__ void cell3(float Mu, float Su, float Mg, float Sg,
                                      float Ml, float Sl, float dd,
                                      float& Mo, float& So) {
    const float mu = fminf(fminf(Mu, Mg), Ml);   // v_min3_f32
    const float eu = exp2g(mu - Mu);
    const float eg = exp2g(mu - Mg);
    const float el = exp2g(mu - Ml);
    So = fmaf(Su, eu, fmaf(Sg, eg, Sl * el));
    Mo = dd + mu;
}

// Inactive-lane word masks: per-column-DISTINCT huge f16 values.
#define MASKW0 0x7BFF7BFFu  /* 65504 */
#define MASKW1 0x70007000u  /* 8192  */
#define MASKW2 0x60006000u  /* 512   */
#define MASKW3 0x50005000u  /* 32    */

// One block = TWO batches, 512 threads (8 waves). Wave->SIMD is wid%4, so:
//   wid 0: consumer batch 0   \ same SIMD -> mutual bubble filling
//   wid 4: consumer batch 1   /
//   wid 1: producer batch 0   \ same SIMD
//   wid 5: producer batch 1   /
//   wid 2,3,6,7: phase-0 help, then exit.
// Producer gate: stripe sg (drows [8sg,8sg+70]) overwrites slots aliasing
// drows <= 8sg-6; consumer publishes prg at steps 8g+2 and 8g+6, so the
// needed value 8sg-6 = 8(sg-1)+2 is exactly published (slack 6 supersteps).
__global__ __launch_bounds__(512, 2) void sdtw_kernel(
    const float* __restrict__ x, const float* __restrict__ y,
    float* __restrict__ out) {
    extern __shared__ __align__(16) char smem[];

    const int tid = threadIdx.x;  // 0..511
    const int wid = tid >> 6;
    const int lane = tid & 63;

    // ---- phase 0 (all 8 waves): norms for both batches + flag init ----
    {
        const int q = tid & 255;   // row
        const int bq = tid >> 8;   // batch within block
        const float* xb0 = x + ((size_t)(2 * blockIdx.x + bq)) * 8192;
        const float* yb0 = y + ((size_t)(2 * blockIdx.x + bq)) * 8192;
        char* base0 = smem + bq * PB;
        float* x2s0 = (float*)(base0 + OFF_X2S);
        float* y2s0 = (float*)(base0 + OFF_Y2S);
        const float4* px = (const float4*)(xb0 + q * 32);
        float s2 = 0.f;
#pragma unroll
        for (int k = 0; k < 8; k++) {
            float4 f = px[k];
            s2 += f.x * f.x + f.y * f.y + f.z * f.z + f.w * f.w;
        }
        x2s0[q] = s2 * LOG2E;
        const float4* py = (const float4*)(yb0 + q * 32);
        float t2 = 0.f;
#pragma unroll
        for (int k = 0; k < 8; k++) {
            float4 f = py[k];
            t2 += f.x * f.x + f.y * f.y + f.z * f.z + f.w * f.w;
        }
        y2s0[q] = t2 * LOG2E;
        if (q < 16) ((volatile int*)(base0 + OFF_RDY))[q] = 0;
        if (q == 16) *(volatile int*)(base0 + OFF_PRG) = 0;
    }
    __syncthreads();

    if (wid == 2 || wid == 3 || wid == 6 || wid == 7) return;

    const int bi = (wid >= 4) ? 1 : 0;
    char* base = smem + bi * PB;
    unsigned char* band = (unsigned char*)base;
    float* x2sL = (float*)(base + OFF_X2S);
    float* y2sL = (float*)(base + OFF_Y2S);
    volatile int* rdy = (volatile int*)(base + OFF_RDY);
    volatile int* prg = (volatile int*)(base + OFF_PRG);
    const float* xb = x + ((size_t)(2 * blockIdx.x + bi)) * 8192;
    const float* yb = y + ((size_t)(2 * blockIdx.x + bi)) * 8192;

    if (wid == 1 || wid == 5) {
        // ================= producer wave =================
        const int qd = lane >> 4, xr = lane & 15;

        half8 yfrag[16];  // B-frags: lane holds y[ci*16+xr][qd*8+j]
        float yvL[16];
#pragma unroll
        for (int ci = 0; ci < 16; ci++) {
            const float* yp = yb + (ci * 16 + xr) * 32 + qd * 8;
            float4 f0 = *(const float4*)yp;
            float4 f1 = *(const float4*)(yp + 4);
            half8 v;
            v[0] = (_Float16)f0.x; v[1] = (_Float16)f0.y;
            v[2] = (_Float16)f0.z; v[3] = (_Float16)f0.w;
            v[4] = (_Float16)f1.x; v[5] = (_Float16)f1.y;
            v[6] = (_Float16)f1.z; v[7] = (_Float16)f1.w;
            yfrag[ci] = v;
            yvL[ci] = y2sL[ci * 16 + xr];
        }
        // stripe-0 A-frag from global (same f32->f16 cast as before)
        half8 xcur;
        {
            const float* xp = xb + xr * 32 + qd * 8;
            float4 f0 = *(const float4*)xp;
            float4 f1 = *(const float4*)(xp + 4);
            half8 v;
            v[0] = (_Float16)f0.x; v[1] = (_Float16)f0.y;
            v[2] = (_Float16)f0.z; v[3] = (_Float16)f0.w;
            v[4] = (_Float16)f1.x; v[5] = (_Float16)f1.y;
            v[6] = (_Float16)f1.z; v[7] = (_Float16)f1.w;
            xcur = v;
        }

        for (int sg = 0; sg < 16; sg++) {
            if (sg >= 1) {
                const int need = 8 * sg - 6;   // = 8(sg-1)+2, a published value
                while (*prg < need) {}
            }
            // lazy prefetch of next stripe's x (latency hidden under MFMAs)
            float4 nf0, nf1;
            const bool pf = (sg < 15);
            if (pf) {
                const float* xp = xb + ((sg + 1) * 16 + xr) * 32 + qd * 8;
                nf0 = *(const float4*)xp;
                nf1 = *(const float4*)(xp + 4);
            }
            const float4 xl = *(const float4*)&x2sL[sg * 16 + qd * 4];
            const int p0 = 8 * sg + 2 * qd;  // global pair of acc[0],acc[1]
#pragma unroll
            for (int ci = 0; ci < 16; ci++) {
                f32x4 acc = {0.f, 0.f, 0.f, 0.f};
                acc = __builtin_amdgcn_mfma_f32_16x16x32_f16(xcur, yfrag[ci], acc, 0, 0, 0);
                const int c = ci * 16 + xr;
                const float yv = yvL[ci];
                const float d0 = fmaxf(fmaf(M2L, acc[0], xl.x + yv), 0.f);
                const float d1 = fmaxf(fmaf(M2L, acc[1], xl.y + yv), 0.f);
                const float d2 = fmaxf(fmaf(M2L, acc[2], xl.z + yv), 0.f);
                const float d3 = fmaxf(fmaf(M2L, acc[3], xl.w + yv), 0.f);
                const half2_t h01 = pkrtz(d0, d1);
                const half2_t h23 = pkrtz(d2, d3);
                const int dr0 = p0 + (c >> 2);          // anti-diagonal row <= 189
                int s0_ = dr0;
                if (s0_ >= RSLOT) s0_ -= RSLOT;
                if (s0_ >= RSLOT) s0_ -= RSLOT;
                int s1_ = dr0 + 1;
                if (s1_ >= RSLOT) s1_ -= RSLOT;
                if (s1_ >= RSLOT) s1_ -= RSLOT;
                *(half2_t*)&band[s0_ * DRB + 4 * c] = h01;
                *(half2_t*)&band[s1_ * DRB + 4 * c] = h23;
            }
            __threadfence_block();  // drain LDS writes before flagging
            if (lane == 0) rdy[sg] = 1;
            if (pf) {
                half8 v;
                v[0] = (_Float16)nf0.x; v[1] = (_Float16)nf0.y;
                v[2] = (_Float16)nf0.z; v[3] = (_Float16)nf0.w;
                v[4] = (_Float16)nf1.x; v[5] = (_Float16)nf1.y;
                v[6] = (_Float16)nf1.z; v[7] = (_Float16)nf1.w;
                xcur = v;
            }
        }
        return;
    }

    // ================= consumer (DP) wave, wid 0 or 4 =================
    float pBM[4], pBS[4];
    pBM[0] = BIG; pBS[0] = 1.f;
    pBM[1] = BIG; pBS[1] = 1.f;
    pBM[2] = BIG; pBS[2] = 1.f;
    pBM[3] = BIG; pBS[3] = 1.f;
    float G0M = (lane == 0) ? 0.f : BIG, G0S = 1.f;
    float MpA3 = BIG, SpA3 = 1.f, MpB3 = BIG, SpB3 = 1.f;

    float dAc[4], dBc[4];  // current decoded inputs

    auto decode = [&](uint4 w, int s1, bool domask) {
        unsigned wx = w.x, wy = w.y, wz = w.z, ww = w.w;
        if (domask) {
            const bool act = (unsigned)(s1 - 1 - lane) < 128u;
            wx = act ? wx : MASKW0;
            wy = act ? wy : MASKW1;
            wz = act ? wz : MASKW2;
            ww = act ? ww : MASKW3;
        }
        dec2(wx, dAc[0], dBc[0]);
        dec2(wy, dAc[1], dBc[1]);
        dec2(wz, dAc[2], dBc[2]);
        dec2(ww, dAc[3], dBc[3]);
    };

    while (rdy[0] == 0) {}
    decode(*(const uint4*)&band[16 * lane], 1, true);  // drow 0 -> step 1

    auto step = [&](int s_, const char* gb, int koff, bool MASKD) {
        const float MLA = shfl_up1(MpA3, BIG);
        const float MLB = shfl_up1(MpB3, BIG);
        const float SLA = shfl_up1(SpA3, 1.f);
        const float SLB = shfl_up1(SpB3, 1.f);

        const uint4 wnext = *(const uint4*)(gb + koff);

        float MA[4], SA[4];
        cell3(pBM[0], pBS[0], G0M, G0S, MLA, SLA, dAc[0], MA[0], SA[0]);
        cell3(pBM[1], pBS[1], pBM[0], pBS[0], MA[0], SA[0], dAc[1], MA[1], SA[1]);
        cell3(pBM[2], pBS[2], pBM[1], pBS[1], MA[1], SA[1], dAc[2], MA[2], SA[2]);
        cell3(pBM[3], pBS[3], pBM[2], pBS[2], MA[2], SA[2], dAc[3], MA[3], SA[3]);

        float MB[4], SB[4];
        cell3(MA[0], SA[0], MLA, SLA, MLB, SLB, dBc[0], MB[0], SB[0]);
        cell3(MA[1], SA[1], MA[0], SA[0], MB[0], SB[0], dBc[1], MB[1], SB[1]);
        cell3(MA[2], SA[2], MA[1], SA[1], MB[1], SB[1], dBc[2], MB[2], SB[2]);
        cell3(MA[3], SA[3], MA[2], SA[2], MB[2], SB[2], dBc[3], MB[3], SB[3]);

        decode(wnext, s_ + 1, MASKD);  // fills spine bubbles at the tail

        MpA3 = MA[3]; SpA3 = SA[3];
        MpB3 = MB[3]; SpB3 = SB[3];
#pragma unroll
        for (int k = 0; k < 4; k++) { pBM[k] = MB[k]; pBS[k] = SB[k]; }
        G0M = MLB; G0S = SLB;
    };

    // prologue: supersteps 1..7; publish prg after steps 2 and 6
    {
        const char* gb0 = (const char*)&band[16 * lane];
        step(1, gb0, 1 * DRB, true);
        step(2, gb0, 2 * DRB, true);
        if (lane == 0) *prg = 2;
        step(3, gb0, 3 * DRB, true);
        step(4, gb0, 4 * DRB, true);
        step(5, gb0, 5 * DRB, true);
        step(6, gb0, 6 * DRB, true);
        if (lane == 0) *prg = 6;
        step(7, gb0, 7 * DRB, true);
    }

    // 23 groups of 8; slot0 = 8g mod 76 maintained incrementally.
    int slot0 = 0;
    for (int g = 1; g < 24; g++) {
        slot0 += 8;
        if (slot0 >= RSLOT) slot0 -= RSLOT;
        int st = (g > 15) ? 15 : g;
        while (rdy[st] == 0) {}
        const int s0 = 8 * g;
        const char* gb = (const char*)&band[slot0 * DRB + 16 * lane];
        if (g == 9) {
            // slot0 == 72: offsets wrap at k>=4; g in [8,15] -> no masking
            const char* gba = (const char*)&band[16 * lane];
#pragma unroll
            for (int k = 0; k < 8; k++) {
                const int sl = (k < 4) ? (72 + k) : (k - 4);
                step(s0 + k, gba, sl * DRB, false);
                if (k == 2 || k == 6) { if (lane == 0) *prg = s0 + k; }
            }
        } else if (g >= 8 && g <= 15) {
#pragma unroll
            for (int k = 0; k < 8; k++) {
                step(s0 + k, gb, k * DRB, false);
                if (k == 2 || k == 6) { if (lane == 0) *prg = s0 + k; }
            }
        } else if (g < 23) {
#pragma unroll
            for (int k = 0; k < 8; k++) {
                step(s0 + k, gb, k * DRB, true);
                if (k == 2 || k == 6) { if (lane == 0) *prg = s0 + k; }
            }
        } else {
            // g==23: steps 184..191; k==7 fetch (step 192) unused -> clamp
#pragma unroll
            for (int k = 0; k < 8; k++) {
                step(s0 + k, gb, (k == 7 ? 6 : k) * DRB, true);
                if (k == 2 || k == 6) { if (lane == 0) *prg = s0 + k; }
            }
        }
    }

    // lane 63's superstep-191 commit is the final cell D[256][256]
    if (lane == 63)
        atomicAdd(out, (MpB3 - log2g(SpB3)) * (LN2 / 256.f));
}

extern "C" void kernel_launch(void* const* d_in, const int* in_sizes, int n_in,
                              void* d_out, int out_size, void* d_ws, size_t ws_size,
                              hipStream_t stream) {
    const float* x = (const float*)d_in[0];
    const float* y = (const float*)d_in[1];
    float* out = (float*)d_out;
    const int B = in_sizes[0] / (256 * 32);  // 256

    (void)hipFuncSetAttribute((const void*)sdtw_kernel,
                              hipFuncAttributeMaxDynamicSharedMemorySize,
                              LDS_BYTES);
    (void)hipMemsetAsync(d_out, 0, sizeof(float), stream);
    sdtw_kernel<<<dim3(B / 2), dim3(512), LDS_BYTES, stream>>>(x, y, out);
}

// Round 10
// 121.014 us; speedup vs baseline: 1.3518x; 1.3518x over previous
//
#include <hip/hip_runtime.h>

#define BIG 1e8f
#define LN2 0.69314718f
#define LOG2E 1.44269504f
#define M2L -2.8853900818f  /* -2*log2(e) */

#define RSLOT 112           /* band ring slots (anti-diagonal rows); 8-divisible */
#define DRB 1040            /* drow stride bytes: 256 cols * 4B(half2) + 16 pad */

/* dynamic LDS layout */
#define OFF_XH   116480     /* band: [0, 116480) = 112*1040 */
#define OFF_X2S  132864     /* xh: 16384 B f16 */
#define OFF_Y2S  133888
#define OFF_RDY  134912     /* 16 ready flags */
#define OFF_PRG  134976     /* consumer progress */
#define LDS_BYTES 135040

typedef _Float16 half8 __attribute__((ext_vector_type(8)));
typedef _Float16 half2_t __attribute__((ext_vector_type(2)));
typedef float f32x4 __attribute__((ext_vector_type(4)));

__device__ __forceinline__ float exp2g(float x) {
#if __has_builtin(__builtin_amdgcn_exp2f)
    return __builtin_amdgcn_exp2f(x);
#else
    return exp2f(x);
#endif
}
__device__ __forceinline__ float log2g(float x) {
#if __has_builtin(__builtin_amdgcn_logf)
    return __builtin_amdgcn_logf(x);
#else
    return log2f(x);
#endif
}

__device__ __forceinline__ half2_t pkrtz(float a, float b) {
    return __builtin_bit_cast(half2_t, __builtin_amdgcn_cvt_pkrtz(a, b));
}

// whole-wave shift-up-by-1 via DPP wave_shr:1; lane 0 receives oldv.
__device__ __forceinline__ float shfl_up1(float v, float oldv) {
    int r = __builtin_amdgcn_update_dpp(
        __builtin_bit_cast(int, oldv), __builtin_bit_cast(int, v),
        0x138 /*wave_shr:1*/, 0xf, 0xf, false);
    return __builtin_bit_cast(float, r);
}

__device__ __forceinline__ void dec2(unsigned int w, float& a, float& b) {
    half2_t h = __builtin_bit_cast(half2_t, w);
    a = (float)h[0];
    b = (float)h[1];
}

// SELECTLESS 3-way softmin cell in exponential-pair form (v = M - log2(S)):
// out = d + softmin{up, diag, left}. mu = min3 -> one exponent is exactly 0
// (exp2(0)=1), the far ones flush to exact 0 -- no cmp/cndmask machinery.
__device__ __forceinline__ void cell3(float Mu, float Su, float Mg, float Sg,
                                      float Ml, float Sl, float dd,
                                      float& Mo, float& So) {
    const float mu = fminf(fminf(Mu, Mg), Ml);   // v_min3_f32
    const float eu = exp2g(mu - Mu);
    const float eg = exp2g(mu - Mg);
    const float el = exp2g(mu - Ml);
    So = fmaf(Su, eu, fmaf(Sg, eg, Sl * el));
    Mo = dd + mu;
}

// Mask words: per-column-DISTINCT huge f16 values. The band ring is PREFILLED
// with this pattern in phase 0, so never-written (invalid-pair) cells decode
// to exactly the values runtime masking used to produce (gen-1 reads).
// Post-window (gen-2 stale) reads need no masking at all: an inactive lane's
// state is only ever relayed to a lane that is already inactive (window ends
// one step later per lane), so garbage never reaches an active value.
#define MASKW0 0x7BFF7BFFu  /* 65504 */
#define MASKW1 0x70007000u  /* 8192  */
#define MASKW2 0x60006000u  /* 512   */
#define MASKW3 0x50005000u  /* 32    */

// One block = one batch, 2 waves on 2 SIMDs.
// Wave 1 (producer): MFMA dist staging into anti-diagonal LDS ring. Proven.
// Wave 0 (consumer): cell3 DP wavefront, software-pipelined (fetch drow s /
//   decode step s+1's inputs at the tail of step s). NO masking anywhere:
//   decode is 8 cvts. Uniform group bodies.
__global__ __launch_bounds__(128, 1) void sdtw_kernel(
    const float* __restrict__ x, const float* __restrict__ y,
    float* __restrict__ out) {
    extern __shared__ __align__(16) char smem[];
    unsigned char* band = (unsigned char*)smem;
    _Float16* xh = (_Float16*)(smem + OFF_XH);
    float* x2sL = (float*)(smem + OFF_X2S);   // row norms * log2(e)
    float* y2sL = (float*)(smem + OFF_Y2S);
    volatile int* rdy = (volatile int*)(smem + OFF_RDY);
    volatile int* prg = (volatile int*)(smem + OFF_PRG);

    const int tid = threadIdx.x;  // 0..127
    const int b = blockIdx.x;
    const float* xb = x + (size_t)b * 8192;
    const float* yb = y + (size_t)b * 8192;

    // ---- phase 0 (both waves): mask-prefill band; stage x; norms; flags ----
    {
        const uint4 mw = {MASKW0, MASKW1, MASKW2, MASKW3};
        uint4* bp = (uint4*)smem;
        for (int i = tid; i < (OFF_XH / 16); i += 128) bp[i] = mw;
    }
#pragma unroll
    for (int rr = 0; rr < 2; rr++) {
        const int r = tid + rr * 128;
        const float4* px = (const float4*)(xb + r * 32);
        union { _Float16 h[32]; half8 v[4]; } uc;
        float s2 = 0.f;
#pragma unroll
        for (int q = 0; q < 8; q++) {
            float4 f = px[q];
            s2 += f.x * f.x + f.y * f.y + f.z * f.z + f.w * f.w;
            uc.h[4 * q + 0] = (_Float16)f.x;
            uc.h[4 * q + 1] = (_Float16)f.y;
            uc.h[4 * q + 2] = (_Float16)f.z;
            uc.h[4 * q + 3] = (_Float16)f.w;
        }
        half8* dst = (half8*)&xh[r * 32];
#pragma unroll
        for (int q = 0; q < 4; q++) dst[q] = uc.v[q];
        x2sL[r] = s2 * LOG2E;

        const float4* py = (const float4*)(yb + r * 32);
        float t2 = 0.f;
#pragma unroll
        for (int q = 0; q < 8; q++) {
            float4 f = py[q];
            t2 += f.x * f.x + f.y * f.y + f.z * f.z + f.w * f.w;
        }
        y2sL[r] = t2 * LOG2E;
    }
    if (tid < 16) rdy[tid] = 0;
    if (tid == 16) *prg = 0;
    __syncthreads();

    if (tid >= 64) {
        // ================= producer wave =================
        const int lane = tid - 64;
        const int qd = lane >> 4, xr = lane & 15;

        half8 yfrag[16];  // B-frags: lane holds y[ci*16+xr][qd*8+j]
        float yvL[16];
#pragma unroll
        for (int ci = 0; ci < 16; ci++) {
            const float* yp = yb + (ci * 16 + xr) * 32 + qd * 8;
            float4 f0 = *(const float4*)yp;
            float4 f1 = *(const float4*)(yp + 4);
            half8 v;
            v[0] = (_Float16)f0.x; v[1] = (_Float16)f0.y;
            v[2] = (_Float16)f0.z; v[3] = (_Float16)f0.w;
            v[4] = (_Float16)f1.x; v[5] = (_Float16)f1.y;
            v[6] = (_Float16)f1.z; v[7] = (_Float16)f1.w;
            yfrag[ci] = v;
            yvL[ci] = y2sL[ci * 16 + xr];
        }

        for (int sg = 0; sg < 16; sg++) {
            // ring-reuse gate: stripe sg touches drows [8sg, 8sg+70]; the
            // aliased drows (d-112) need consumer progress >= 8sg-40.
            if (sg >= 6) {
                const int need = 8 * sg - 40;
                while (*prg < need) {}
            }
            const half8 xf = *(const half8*)&xh[(sg * 16 + xr) * 32 + qd * 8];
            const float4 xl = *(const float4*)&x2sL[sg * 16 + qd * 4];
            const int p0 = 8 * sg + 2 * qd;  // global pair of acc[0],acc[1]
#pragma unroll
            for (int ci = 0; ci < 16; ci++) {
                f32x4 acc = {0.f, 0.f, 0.f, 0.f};
                acc = __builtin_amdgcn_mfma_f32_16x16x32_f16(xf, yfrag[ci], acc, 0, 0, 0);
                const int c = ci * 16 + xr;
                const float yv = yvL[ci];
                const float d0 = fmaxf(fmaf(M2L, acc[0], xl.x + yv), 0.f);
                const float d1 = fmaxf(fmaf(M2L, acc[1], xl.y + yv), 0.f);
                const float d2 = fmaxf(fmaf(M2L, acc[2], xl.z + yv), 0.f);
                const float d3 = fmaxf(fmaf(M2L, acc[3], xl.w + yv), 0.f);
                const half2_t h01 = pkrtz(d0, d1);
                const half2_t h23 = pkrtz(d2, d3);
                const int dr0 = p0 + (c >> 2);          // anti-diagonal row
                int s0_ = dr0;     if (s0_ >= RSLOT) s0_ -= RSLOT;
                int s1_ = dr0 + 1; if (s1_ >= RSLOT) s1_ -= RSLOT;
                *(half2_t*)&band[s0_ * DRB + 4 * c] = h01;
                *(half2_t*)&band[s1_ * DRB + 4 * c] = h23;
            }
            __threadfence_block();  // drain LDS writes before flagging
            if (lane == 0) rdy[sg] = 1;
        }
        return;
    }

    // ================= consumer (DP) wave =================
    const int lane = tid;
    // previous-B-row pairs (raw, no premerge) + prev diag-relay pair G0
    float pBM[4], pBS[4];
    pBM[0] = BIG; pBS[0] = 1.f;
    pBM[1] = BIG; pBS[1] = 1.f;
    pBM[2] = BIG; pBS[2] = 1.f;
    pBM[3] = BIG; pBS[3] = 1.f;
    float G0M = (lane == 0) ? 0.f : BIG, G0S = 1.f;
    float MpA3 = BIG, SpA3 = 1.f, MpB3 = BIG, SpB3 = 1.f;

    float dAc[4], dBc[4];  // current decoded inputs

    auto decode = [&](uint4 w) {
        dec2(w.x, dAc[0], dBc[0]);
        dec2(w.y, dAc[1], dBc[1]);
        dec2(w.z, dAc[2], dBc[2]);
        dec2(w.w, dAc[3], dBc[3]);
    };

    while (rdy[0] == 0) {}
    decode(*(const uint4*)&band[16 * lane]);  // drow 0 -> step 1

    // one superstep: fetch the next drow (inputs for the next step) from
    // gb+koff, run 8 cells on current decoded inputs, decode the fetched
    // row at the tail (fills spine bubbles), commit.
    auto step = [&](const char* gb, int koff) {
        const float MLA = shfl_up1(MpA3, BIG);
        const float MLB = shfl_up1(MpB3, BIG);
        const float SLA = shfl_up1(SpA3, 1.f);
        const float SLB = shfl_up1(SpB3, 1.f);

        const uint4 wnext = *(const uint4*)(gb + koff);

        // A-row: cell k = 3way(up=pB[k], diag=(k?pB[k-1]:G0), left=chain)
        float MA[4], SA[4];
        cell3(pBM[0], pBS[0], G0M, G0S, MLA, SLA, dAc[0], MA[0], SA[0]);
        cell3(pBM[1], pBS[1], pBM[0], pBS[0], MA[0], SA[0], dAc[1], MA[1], SA[1]);
        cell3(pBM[2], pBS[2], pBM[1], pBS[1], MA[1], SA[1], dAc[2], MA[2], SA[2]);
        cell3(pBM[3], pBS[3], pBM[2], pBS[2], MA[2], SA[2], dAc[3], MA[3], SA[3]);

        // B-row: cell k = 3way(up=A[k], diag=(k?A[k-1]:MLA-relay), left=chain)
        float MB[4], SB[4];
        cell3(MA[0], SA[0], MLA, SLA, MLB, SLB, dBc[0], MB[0], SB[0]);
        cell3(MA[1], SA[1], MA[0], SA[0], MB[0], SB[0], dBc[1], MB[1], SB[1]);
        cell3(MA[2], SA[2], MA[1], SA[1], MB[1], SB[1], dBc[2], MB[2], SB[2]);
        cell3(MA[3], SA[3], MA[2], SA[2], MB[2], SB[2], dBc[3], MB[3], SB[3]);

        decode(wnext);  // next step's inputs; no masking needed (see above)

        MpA3 = MA[3]; SpA3 = SA[3];
        MpB3 = MB[3]; SpB3 = SB[3];
#pragma unroll
        for (int k = 0; k < 4; k++) { pBM[k] = MB[k]; pBS[k] = SB[k]; }
        G0M = MLB; G0S = SLB;
    };

    // prologue: supersteps 1..7 (stripe 0 covers drows 0..7)
    {
        const char* gb0 = (const char*)&band[16 * lane];
#pragma unroll
        for (int s_ = 1; s_ < 8; s_++) step(gb0, s_ * DRB);
    }

    // 23 groups of 8 supersteps; poll/publish at group head; group-shared
    // fetch base (RSLOT=112 is 8-divisible -> no wrap within a group).
    for (int g = 1; g < 24; g++) {
        int st = (g > 15) ? 15 : g;
        while (rdy[st] == 0) {}
        if (lane == 0) *prg = 8 * g;
        const int s0 = 8 * g;
        const int slot0 = (s0 >= RSLOT) ? s0 - RSLOT : s0;  // s0 <= 184 < 224
        const char* gb = (const char*)&band[slot0 * DRB + 16 * lane];
        if (g < 23) {
#pragma unroll
            for (int k = 0; k < 8; k++) step(gb, k * DRB);
        } else {
            // g==23: steps 184..191; k==7 fetch (for step 192) is unused --
            // clamp its offset to drow 190's slot at compile time.
#pragma unroll
            for (int k = 0; k < 8; k++) step(gb, (k == 7 ? 6 : k) * DRB);
        }
    }

    // lane 63's superstep-191 commit is the final cell D[256][256]
    if (lane == 63)
        atomicAdd(out, (MpB3 - log2g(SpB3)) * (LN2 / 256.f));
}

extern "C" void kernel_launch(void* const* d_in, const int* in_sizes, int n_in,
                              void* d_out, int out_size, void* d_ws, size_t ws_size,
                              hipStream_t stream) {
    const float* x = (const float*)d_in[0];
    const float* y = (const float*)d_in[1];
    float* out = (float*)d_out;
    const int B = in_sizes[0] / (256 * 32);  // 256

    (void)hipFuncSetAttribute((const void*)sdtw_kernel,
                              hipFuncAttributeMaxDynamicSharedMemorySize,
                              LDS_BYTES);
    (void)hipMemsetAsync(d_out, 0, sizeof(float), stream);
    sdtw_kernel<<<dim3(B), dim3(128), LDS_BYTES, stream>>>(x, y, out);
}

// Round 11
// 120.277 us; speedup vs baseline: 1.3601x; 1.0061x over previous
//
#include <hip/hip_runtime.h>

#define BIG 1e8f
#define LN2 0.69314718f
#define LOG2E 1.44269504f
#define M2L -2.8853900818f  /* -2*log2(e) */

#define RSLOT 112           /* band ring slots (anti-diagonal rows); 8-divisible */
#define DRB 1040            /* drow stride bytes: 256 cols * 4B(half2) + 16 pad */

/* dynamic LDS layout */
#define OFF_XH   116480     /* band: [0, 116480) = 112*1040 */
#define OFF_X2S  132864     /* xh: 16384 B f16 */
#define OFF_Y2S  133888
#define OFF_RDY  134912     /* 16 ready flags */
#define OFF_PRG  134976     /* consumer progress */
#define LDS_BYTES 135040

typedef _Float16 half8 __attribute__((ext_vector_type(8)));
typedef _Float16 half2_t __attribute__((ext_vector_type(2)));
typedef float f32x4 __attribute__((ext_vector_type(4)));

__device__ __forceinline__ float exp2g(float x) {
#if __has_builtin(__builtin_amdgcn_exp2f)
    return __builtin_amdgcn_exp2f(x);
#else
    return exp2f(x);
#endif
}
__device__ __forceinline__ float log2g(float x) {
#if __has_builtin(__builtin_amdgcn_logf)
    return __builtin_amdgcn_logf(x);
#else
    return log2f(x);
#endif
}

__device__ __forceinline__ half2_t pkrtz(float a, float b) {
    return __builtin_bit_cast(half2_t, __builtin_amdgcn_cvt_pkrtz(a, b));
}

// whole-wave shift-up-by-1 via DPP wave_shr:1; lane 0 receives oldv.
__device__ __forceinline__ float shfl_up1(float v, float oldv) {
    int r = __builtin_amdgcn_update_dpp(
        __builtin_bit_cast(int, oldv), __builtin_bit_cast(int, v),
        0x138 /*wave_shr:1*/, 0xf, 0xf, false);
    return __builtin_bit_cast(float, r);
}

__device__ __forceinline__ void dec2(unsigned int w, float& a, float& b) {
    half2_t h = __builtin_bit_cast(half2_t, w);
    a = (float)h[0];
    b = (float)h[1];
}

// SELECTLESS 3-way softmin cell, LATENCY-REASSOCIATED.
// out = d + softmin{up, diag, left}; pair form v = M - log2(S).
// Key: the left-neighbor's S enters via the OUTERMOST fma, and the exp2 of
// the left-M delta feeds only that fma. So the cell-to-cell S dependency is
// ONE fma, and exp2 latency is a fixed per-cell offset off the fast M-chain
// (min3+add), not chain-accumulating.
__device__ __forceinline__ void cell3(float Mu, float Su, float Mg, float Sg,
                                      float Ml, float Sl, float dd,
                                      float& Mo, float& So) {
    const float mu = fminf(fminf(Mu, Mg), Ml);   // v_min3_f32
    const float eu = exp2g(mu - Mu);
    const float eg = exp2g(mu - Mg);
    const float el = exp2g(mu - Ml);
    const float pre = fmaf(Su, eu, Sg * eg);     // off the S-chain
    So = fmaf(Sl, el, pre);                      // single dep on left S
    Mo = dd + mu;
}

// Mask words: per-column-DISTINCT huge f16 values. The band ring is PREFILLED
// with this pattern in phase 0, so never-written (invalid-pair) cells decode
// to exactly the values runtime masking used to produce (gen-1 reads).
// Post-window (gen-2 stale) reads need no masking: an inactive lane's state
// is only ever relayed to a lane that is already inactive.
#define MASKW0 0x7BFF7BFFu  /* 65504 */
#define MASKW1 0x70007000u  /* 8192  */
#define MASKW2 0x60006000u  /* 512   */
#define MASKW3 0x50005000u  /* 32    */

// One block = one batch, 2 waves on 2 SIMDs.
// Wave 1 (producer): MFMA dist staging into anti-diagonal LDS ring. Proven.
// Wave 0 (consumer): cell3 DP wavefront, software-pipelined (fetch drow s /
//   decode step s+1's inputs at the tail of step s). No masking anywhere.
__global__ __launch_bounds__(128, 1) void sdtw_kernel(
    const float* __restrict__ x, const float* __restrict__ y,
    float* __restrict__ out) {
    extern __shared__ __align__(16) char smem[];
    unsigned char* band = (unsigned char*)smem;
    _Float16* xh = (_Float16*)(smem + OFF_XH);
    float* x2sL = (float*)(smem + OFF_X2S);   // row norms * log2(e)
    float* y2sL = (float*)(smem + OFF_Y2S);
    volatile int* rdy = (volatile int*)(smem + OFF_RDY);
    volatile int* prg = (volatile int*)(smem + OFF_PRG);

    const int tid = threadIdx.x;  // 0..127
    const int b = blockIdx.x;
    const float* xb = x + (size_t)b * 8192;
    const float* yb = y + (size_t)b * 8192;

    // ---- phase 0 (both waves): mask-prefill band; stage x; norms; flags ----
    {
        const uint4 mw = {MASKW0, MASKW1, MASKW2, MASKW3};
        uint4* bp = (uint4*)smem;
        for (int i = tid; i < (OFF_XH / 16); i += 128) bp[i] = mw;
    }
#pragma unroll
    for (int rr = 0; rr < 2; rr++) {
        const int r = tid + rr * 128;
        const float4* px = (const float4*)(xb + r * 32);
        union { _Float16 h[32]; half8 v[4]; } uc;
        float s2 = 0.f;
#pragma unroll
        for (int q = 0; q < 8; q++) {
            float4 f = px[q];
            s2 += f.x * f.x + f.y * f.y + f.z * f.z + f.w * f.w;
            uc.h[4 * q + 0] = (_Float16)f.x;
            uc.h[4 * q + 1] = (_Float16)f.y;
            uc.h[4 * q + 2] = (_Float16)f.z;
            uc.h[4 * q + 3] = (_Float16)f.w;
        }
        half8* dst = (half8*)&xh[r * 32];
#pragma unroll
        for (int q = 0; q < 4; q++) dst[q] = uc.v[q];
        x2sL[r] = s2 * LOG2E;

        const float4* py = (const float4*)(yb + r * 32);
        float t2 = 0.f;
#pragma unroll
        for (int q = 0; q < 8; q++) {
            float4 f = py[q];
            t2 += f.x * f.x + f.y * f.y + f.z * f.z + f.w * f.w;
        }
        y2sL[r] = t2 * LOG2E;
    }
    if (tid < 16) rdy[tid] = 0;
    if (tid == 16) *prg = 0;
    __syncthreads();

    if (tid >= 64) {
        // ================= producer wave =================
        const int lane = tid - 64;
        const int qd = lane >> 4, xr = lane & 15;

        half8 yfrag[16];  // B-frags: lane holds y[ci*16+xr][qd*8+j]
        float yvL[16];
#pragma unroll
        for (int ci = 0; ci < 16; ci++) {
            const float* yp = yb + (ci * 16 + xr) * 32 + qd * 8;
            float4 f0 = *(const float4*)yp;
            float4 f1 = *(const float4*)(yp + 4);
            half8 v;
            v[0] = (_Float16)f0.x; v[1] = (_Float16)f0.y;
            v[2] = (_Float16)f0.z; v[3] = (_Float16)f0.w;
            v[4] = (_Float16)f1.x; v[5] = (_Float16)f1.y;
            v[6] = (_Float16)f1.z; v[7] = (_Float16)f1.w;
            yfrag[ci] = v;
            yvL[ci] = y2sL[ci * 16 + xr];
        }

        for (int sg = 0; sg < 16; sg++) {
            // ring-reuse gate: stripe sg touches drows [8sg, 8sg+70]; the
            // aliased drows (d-112) need consumer progress >= 8sg-40.
            if (sg >= 6) {
                const int need = 8 * sg - 40;
                while (*prg < need) {}
            }
            const half8 xf = *(const half8*)&xh[(sg * 16 + xr) * 32 + qd * 8];
            const float4 xl = *(const float4*)&x2sL[sg * 16 + qd * 4];
            const int p0 = 8 * sg + 2 * qd;  // global pair of acc[0],acc[1]
#pragma unroll
            for (int ci = 0; ci < 16; ci++) {
                f32x4 acc = {0.f, 0.f, 0.f, 0.f};
                acc = __builtin_amdgcn_mfma_f32_16x16x32_f16(xf, yfrag[ci], acc, 0, 0, 0);
                const int c = ci * 16 + xr;
                const float yv = yvL[ci];
                const float d0 = fmaxf(fmaf(M2L, acc[0], xl.x + yv), 0.f);
                const float d1 = fmaxf(fmaf(M2L, acc[1], xl.y + yv), 0.f);
                const float d2 = fmaxf(fmaf(M2L, acc[2], xl.z + yv), 0.f);
                const float d3 = fmaxf(fmaf(M2L, acc[3], xl.w + yv), 0.f);
                const half2_t h01 = pkrtz(d0, d1);
                const half2_t h23 = pkrtz(d2, d3);
                const int dr0 = p0 + (c >> 2);          // anti-diagonal row
                int s0_ = dr0;     if (s0_ >= RSLOT) s0_ -= RSLOT;
                int s1_ = dr0 + 1; if (s1_ >= RSLOT) s1_ -= RSLOT;
                *(half2_t*)&band[s0_ * DRB + 4 * c] = h01;
                *(half2_t*)&band[s1_ * DRB + 4 * c] = h23;
            }
            __threadfence_block();  // drain LDS writes before flagging
            if (lane == 0) rdy[sg] = 1;
        }
        return;
    }

    // ================= consumer (DP) wave =================
    const int lane = tid;
    // previous-B-row pairs (raw, no premerge) + prev diag-relay pair G0
    float pBM[4], pBS[4];
    pBM[0] = BIG; pBS[0] = 1.f;
    pBM[1] = BIG; pBS[1] = 1.f;
    pBM[2] = BIG; pBS[2] = 1.f;
    pBM[3] = BIG; pBS[3] = 1.f;
    float G0M = (lane == 0) ? 0.f : BIG, G0S = 1.f;
    float MpA3 = BIG, SpA3 = 1.f, MpB3 = BIG, SpB3 = 1.f;

    float dAc[4], dBc[4];  // current decoded inputs

    auto decode = [&](uint4 w) {
        dec2(w.x, dAc[0], dBc[0]);
        dec2(w.y, dAc[1], dBc[1]);
        dec2(w.z, dAc[2], dBc[2]);
        dec2(w.w, dAc[3], dBc[3]);
    };

    while (rdy[0] == 0) {}
    decode(*(const uint4*)&band[16 * lane]);  // drow 0 -> step 1

    // one superstep: fetch the next drow (inputs for the next step) from
    // gb+koff, run 8 cells on current decoded inputs, decode the fetched
    // row at the tail (fills spine bubbles), commit.
    auto step = [&](const char* gb, int koff) {
        const float MLA = shfl_up1(MpA3, BIG);
        const float MLB = shfl_up1(MpB3, BIG);
        const float SLA = shfl_up1(SpA3, 1.f);
        const float SLB = shfl_up1(SpB3, 1.f);

        const uint4 wnext = *(const uint4*)(gb + koff);

        // A-row: cell k = 3way(up=pB[k], diag=(k?pB[k-1]:G0), left=chain)
        float MA[4], SA[4];
        cell3(pBM[0], pBS[0], G0M, G0S, MLA, SLA, dAc[0], MA[0], SA[0]);
        cell3(pBM[1], pBS[1], pBM[0], pBS[0], MA[0], SA[0], dAc[1], MA[1], SA[1]);
        cell3(pBM[2], pBS[2], pBM[1], pBS[1], MA[1], SA[1], dAc[2], MA[2], SA[2]);
        cell3(pBM[3], pBS[3], pBM[2], pBS[2], MA[2], SA[2], dAc[3], MA[3], SA[3]);

        // B-row: cell k = 3way(up=A[k], diag=(k?A[k-1]:MLA-relay), left=chain)
        float MB[4], SB[4];
        cell3(MA[0], SA[0], MLA, SLA, MLB, SLB, dBc[0], MB[0], SB[0]);
        cell3(MA[1], SA[1], MA[0], SA[0], MB[0], SB[0], dBc[1], MB[1], SB[1]);
        cell3(MA[2], SA[2], MA[1], SA[1], MB[1], SB[1], dBc[2], MB[2], SB[2]);
        cell3(MA[3], SA[3], MA[2], SA[2], MB[2], SB[2], dBc[3], MB[3], SB[3]);

        decode(wnext);  // next step's inputs; no masking needed

        MpA3 = MA[3]; SpA3 = SA[3];
        MpB3 = MB[3]; SpB3 = SB[3];
#pragma unroll
        for (int k = 0; k < 4; k++) { pBM[k] = MB[k]; pBS[k] = SB[k]; }
        G0M = MLB; G0S = SLB;
    };

    // prologue: supersteps 1..7 (stripe 0 covers drows 0..7)
    {
        const char* gb0 = (const char*)&band[16 * lane];
#pragma unroll
        for (int s_ = 1; s_ < 8; s_++) step(gb0, s_ * DRB);
    }

    // 23 groups of 8 supersteps; poll/publish at group head; group-shared
    // fetch base (RSLOT=112 is 8-divisible -> no wrap within a group).
    for (int g = 1; g < 24; g++) {
        int st = (g > 15) ? 15 : g;
        while (rdy[st] == 0) {}
        if (lane == 0) *prg = 8 * g;
        const int s0 = 8 * g;
        const int slot0 = (s0 >= RSLOT) ? s0 - RSLOT : s0;  // s0 <= 184 < 224
        const char* gb = (const char*)&band[slot0 * DRB + 16 * lane];
        if (g < 23) {
#pragma unroll
            for (int k = 0; k < 8; k++) step(gb, k * DRB);
        } else {
            // g==23: steps 184..191; k==7 fetch (for step 192) is unused --
            // clamp its offset to drow 190's slot at compile time.
#pragma unroll
            for (int k = 0; k < 8; k++) step(gb, (k == 7 ? 6 : k) * DRB);
        }
    }

    // lane 63's superstep-191 commit is the final cell D[256][256]
    if (lane == 63)
        atomicAdd(out, (MpB3 - log2g(SpB3)) * (LN2 / 256.f));
}

extern "C" void kernel_launch(void* const* d_in, const int* in_sizes, int n_in,
                              void* d_out, int out_size, void* d_ws, size_t ws_size,
                              hipStream_t stream) {
    const float* x = (const float*)d_in[0];
    const float* y = (const float*)d_in[1];
    float* out = (float*)d_out;
    const int B = in_sizes[0] / (256 * 32);  // 256

    (void)hipFuncSetAttribute((const void*)sdtw_kernel,
                              hipFuncAttributeMaxDynamicSharedMemorySize,
                              LDS_BYTES);
    (void)hipMemsetAsync(d_out, 0, sizeof(float), stream);
    sdtw_kernel<<<dim3(B), dim3(128), LDS_BYTES, stream>>>(x, y, out);
}